// Round 8
// baseline (878.865 us; speedup 1.0000x reference)
//
#include <hip/hip_runtime.h>

typedef _Float16 h16;
typedef _Float16 h16x2 __attribute__((ext_vector_type(2)));
typedef _Float16 h16x4 __attribute__((ext_vector_type(4)));
typedef _Float16 h16x8 __attribute__((ext_vector_type(8)));
typedef float f32x4 __attribute__((ext_vector_type(4)));

static constexpr int NN   = 20000;   // nodes
static constexpr int NPAD = 20224;   // padded to 256-row tiles (79*256)
static constexpr int NE0  = 120000;  // raw edges
static constexpr int NE   = 140000;  // + self loops
static constexpr int NG   = 512;     // graphs
static constexpr int FIN  = 300;
static constexpr int K1P  = 384;     // FIN padded to K%64==0
static constexpr int CD   = 256;     // channels per head
static constexpr float SLOPE = 0.2f;

#define GLDS16(gsrc, ldst)                                                              \
  __builtin_amdgcn_global_load_lds(                                                    \
      (const __attribute__((address_space(1))) unsigned int*)(gsrc),                    \
      (__attribute__((address_space(3))) unsigned int*)(ldst), 16, 0, 0)

// ---------- input conversion ----------
__global__ __launch_bounds__(256) void fill_x_kernel(const float* __restrict__ x, h16* __restrict__ a1) {
  int r = blockIdx.x;
  for (int c = threadIdx.x; c < K1P; c += 256) {
    float v = (r < NN && c < FIN) ? x[(size_t)r * FIN + c] : 0.f;
    a1[(size_t)r * K1P + c] = (h16)v;
  }
}

__global__ __launch_bounds__(256) void conv_w2_kernel(const float* __restrict__ wl, const float* __restrict__ wr,
                                                      h16* __restrict__ o, int rows, int cols, int colsp) {
  int r = blockIdx.x;  // 0 .. 2*rows-1
  const float* s = (r < rows) ? (wl + (size_t)r * cols) : (wr + (size_t)(r - rows) * cols);
  for (int c = threadIdx.x; c < colsp; c += 256) {
    float v = (c < cols) ? s[c] : 0.f;
    o[(size_t)r * colsp + c] = (h16)v;
  }
}

__global__ __launch_bounds__(256) void attcvt_kernel(const float* __restrict__ a, h16* __restrict__ o, int n) {
  int i = blockIdx.x * 256 + threadIdx.x;
  if (i < n) o[i] = (h16)a[i];
}

// ---------- CSR build ----------
__global__ __launch_bounds__(256) void build_edges_kernel(const int* __restrict__ ei,
                                                          int* __restrict__ src, int* __restrict__ dst) {
  int e = blockIdx.x * 256 + threadIdx.x;
  if (e >= NE) return;
  if (e < NE0) { src[e] = ei[e]; dst[e] = ei[NE0 + e]; }
  else         { src[e] = e - NE0; dst[e] = e - NE0; }
}

__global__ __launch_bounds__(256) void deg_kernel(const int* __restrict__ dst, int* __restrict__ deg) {
  int e = blockIdx.x * 256 + threadIdx.x;
  if (e < NE) atomicAdd(&deg[dst[e]], 1);
}

__global__ __launch_bounds__(1024) void scan_kernel(const int* __restrict__ deg, int* __restrict__ rowptr) {
  __shared__ int b0[1024], b1[1024];
  __shared__ int carry;
  int t = threadIdx.x;
  if (t == 0) carry = 0;
  __syncthreads();
  for (int base = 0; base < NN; base += 1024) {
    int x = (base + t < NN) ? deg[base + t] : 0;
    b0[t] = x;
    __syncthreads();
    int* cur = b0; int* nxt = b1;
    for (int off = 1; off < 1024; off <<= 1) {
      int v = cur[t];
      if (t >= off) v += cur[t - off];
      nxt[t] = v;
      __syncthreads();
      int* tmp = cur; cur = nxt; nxt = tmp;
    }
    if (base + t < NN) rowptr[base + t] = carry + cur[t] - x;  // exclusive
    __syncthreads();
    if (t == 0) carry += cur[1023];
    __syncthreads();
  }
  if (t == 0) rowptr[NN] = carry;
}

__global__ __launch_bounds__(256) void scatter_kernel(const int* __restrict__ src, const int* __restrict__ dst,
                                                      const int* __restrict__ rowptr, int* __restrict__ cursor,
                                                      int* __restrict__ esrc) {
  int e = blockIdx.x * 256 + threadIdx.x;
  if (e >= NE) return;
  int d = dst[e];
  int pos = rowptr[d] + atomicAdd(&cursor[d], 1);
  esrc[pos] = src[e];
}

// ---------- fp16 MFMA GEMM, 256x256 tile, BK=64, 8 waves, counted-vmcnt pipeline ----------
__global__ __launch_bounds__(512, 2) void gemm256_kernel(const h16* __restrict__ A, const h16* __restrict__ B,
                                                         h16* __restrict__ Co, int K, int Nw, int ntN) {
  __shared__ __align__(16) h16 lds[4 * 16384];  // [buf][mat] regions of 256x64
  int nwg = gridDim.x;
  int q = nwg >> 3, r = nwg & 7;
  int xc = blockIdx.x & 7, idx = blockIdx.x >> 3;
  int logical = (xc < r ? xc * (q + 1) : r * (q + 1) + (xc - r) * q) + idx;
  int tm = (logical / ntN) * 256, tn = (logical % ntN) * 256;

  int tid = threadIdx.x;
  int wv = tid >> 6, lane = tid & 63;
  int wm = (wv >> 2) * 128, wn = (wv & 3) * 64;
  int lrow = lane & 15, kq = lane >> 4, lr7 = lrow & 7;

  int rowoff = tid >> 3;
  int ug = ((tid & 7) ^ (rowoff & 7)) * 8;  // pre-swizzled global 16B-unit (in h16 elems)
  int ldsoff = (tid >> 6) * 512;

  const int NT = K >> 6;

  auto STAGE = [&](int buf, int kt) {
#pragma unroll
    for (int j = 0; j < 4; ++j) {
      GLDS16(A + (size_t)(tm + j * 64 + rowoff) * K + kt * 64 + ug,
             &lds[(buf * 2 + 0) * 16384 + j * 4096 + ldsoff]);
      GLDS16(B + (size_t)(tn + j * 64 + rowoff) * K + kt * 64 + ug,
             &lds[(buf * 2 + 1) * 16384 + j * 4096 + ldsoff]);
    }
  };

  STAGE(0, 0);
  STAGE(1, 1);

  f32x4 acc[8][4] = {};
  for (int t = 0; t < NT; ++t) {
    int b = t & 1;
    if (t + 1 < NT) { asm volatile("s_waitcnt vmcnt(8)" ::: "memory"); }
    else            { asm volatile("s_waitcnt vmcnt(0)" ::: "memory"); }
    __builtin_amdgcn_s_barrier();  // all waves' portions of buffer b have landed

    const h16* As_ = &lds[(b * 2 + 0) * 16384];
    const h16* Bs_ = &lds[(b * 2 + 1) * 16384];
    h16x8 af[8], bf[4];
#pragma unroll
    for (int i = 0; i < 8; ++i) af[i] = *(const h16x8*)&As_[(wm + i * 16 + lrow) * 64 + ((kq ^ lr7) * 8)];
#pragma unroll
    for (int j = 0; j < 4; ++j) bf[j] = *(const h16x8*)&Bs_[(wn + j * 16 + lrow) * 64 + ((kq ^ lr7) * 8)];
#pragma unroll
    for (int i = 0; i < 8; ++i)
#pragma unroll
      for (int j = 0; j < 4; ++j)
        acc[i][j] = __builtin_amdgcn_mfma_f32_16x16x32_f16(af[i], bf[j], acc[i][j], 0, 0, 0);
#pragma unroll
    for (int i = 0; i < 8; ++i) af[i] = *(const h16x8*)&As_[(wm + i * 16 + lrow) * 64 + (((4 + kq) ^ lr7) * 8)];
#pragma unroll
    for (int j = 0; j < 4; ++j) bf[j] = *(const h16x8*)&Bs_[(wn + j * 16 + lrow) * 64 + (((4 + kq) ^ lr7) * 8)];
    asm volatile("s_waitcnt lgkmcnt(0)" ::: "memory");
    __builtin_amdgcn_sched_barrier(0);
    __builtin_amdgcn_s_barrier();  // all waves done reading buffer b -> safe to restage
    if (t + 2 < NT) STAGE(b, t + 2);
    __builtin_amdgcn_s_setprio(1);
#pragma unroll
    for (int i = 0; i < 8; ++i)
#pragma unroll
      for (int j = 0; j < 4; ++j)
        acc[i][j] = __builtin_amdgcn_mfma_f32_16x16x32_f16(af[i], bf[j], acc[i][j], 0, 0, 0);
    __builtin_amdgcn_s_setprio(0);
  }

  int cr = kq * 4, cc = lrow;
#pragma unroll
  for (int i = 0; i < 8; ++i)
#pragma unroll
    for (int j = 0; j < 4; ++j) {
      size_t base = (size_t)(tm + wm + i * 16 + cr) * Nw + (tn + wn + j * 16 + cc);
#pragma unroll
      for (int qq = 0; qq < 4; qq++) Co[base + (size_t)qq * Nw] = (h16)acc[i][j][qq];
    }
}

// ---------- fused score + online-softmax + aggregate: WAVE PER (NODE, HEAD-PAIR) ----------
// X row: [ xl (HC) | xr (HC) ], ROWB = 4*HC bytes. Lane owns 8 contiguous ch (16B gather);
// 32-lane group = one head; 5 shuffles reduce both heads of the pair at once.
// Chunk = 16 edges, all gathers issued before any consume (16KB inflight/wave).
// Chunk-level deferred max rescale. No LDS, no __syncthreads, fully independent waves.
// MODE 0: elu(agg+bias) -> fp16 outA.  MODE 1: head-pair sums -> Fb3[n][NS][CD] fp32.
template <int H, int MODE>
__global__ __launch_bounds__(256, 4) void sagg_kernel(
    const h16* __restrict__ X, const int* __restrict__ rowptr, const int* __restrict__ esrc,
    const h16* __restrict__ attH, const float* __restrict__ bias,
    h16* __restrict__ outA, float* __restrict__ Fb3) {
  constexpr int NS = H / 2;
  constexpr int HC = H * CD;
  constexpr unsigned ROWB = (unsigned)(4 * HC);
  int flat = blockIdx.x * 4 + (threadIdx.x >> 6);
  if (flat >= NN * NS) return;
  int n = flat / NS, s = flat - n * NS;
  int lane = threadIdx.x & 63;
  unsigned sby = (unsigned)s * 1024u + (unsigned)lane * 16u;  // byte offset in xl
  const char* Xb = (const char*)X;

  h16x8 xr8 = *(const h16x8*)(Xb + (unsigned)n * ROWB + (unsigned)(2 * HC) + sby);
  h16x8 aw8 = *(const h16x8*)((const char*)attH + sby);
  int beg = rowptr[n], end = rowptr[n + 1];

  float m = -1e30f, den = 0.f;
  float acc[8] = {0.f, 0.f, 0.f, 0.f, 0.f, 0.f, 0.f, 0.f};

  for (int i = beg; i < end; i += 16) {
    int cn = end - i; if (cn > 16) cn = 16;
    h16x8 xv[16];
#pragma unroll
    for (int k = 0; k < 16; ++k) {
      int idx = i + k; if (idx >= end) idx = end - 1;
      xv[k] = *(const h16x8*)(Xb + (unsigned)esrc[idx] * ROWB + sby);  // 16 independent gathers
    }
    float ps[16];
#pragma unroll
    for (int k = 0; k < 16; ++k) {
      h16x8 v = xv[k] + xr8;                       // v_pk_add_f16 x4
      h16x8 u = v * (h16)SLOPE;                    // v_pk_mul_f16 x4
      v = __builtin_elementwise_max(v, u);         // v_pk_max_f16 x4 (leaky_relu)
      float p = 0.f;
      p = __builtin_amdgcn_fdot2(__builtin_shufflevector(v, v, 0, 1), __builtin_shufflevector(aw8, aw8, 0, 1), p, false);
      p = __builtin_amdgcn_fdot2(__builtin_shufflevector(v, v, 2, 3), __builtin_shufflevector(aw8, aw8, 2, 3), p, false);
      p = __builtin_amdgcn_fdot2(__builtin_shufflevector(v, v, 4, 5), __builtin_shufflevector(aw8, aw8, 4, 5), p, false);
      p = __builtin_amdgcn_fdot2(__builtin_shufflevector(v, v, 6, 7), __builtin_shufflevector(aw8, aw8, 6, 7), p, false);
      p += __shfl_xor(p, 1);  p += __shfl_xor(p, 2);  p += __shfl_xor(p, 4);
      p += __shfl_xor(p, 8);  p += __shfl_xor(p, 16);  // 32-lane head group
      ps[k] = p;
    }
    float pm = ps[0];
#pragma unroll
    for (int k = 1; k < 16; ++k) pm = fmaxf(pm, ps[k]);  // dup entries are valid scores
    float nm = fmaxf(m, pm);
    float f = __expf(m - nm);                            // single rescale per chunk
    den *= f;
#pragma unroll
    for (int j = 0; j < 8; ++j) acc[j] *= f;
#pragma unroll
    for (int k = 0; k < 16; ++k) {
      float we = (k < cn) ? __expf(ps[k] - nm) : 0.f;
      den += we;
#pragma unroll
      for (int j = 0; j < 8; ++j) acc[j] += we * (float)xv[k][j];  // v_fma_mix
    }
    m = nm;
  }
  float inv = 1.f / (den + 1e-16f);

  if (MODE == 0) {
    const float* bp = bias + s * 512 + lane * 8;
    float4 b0 = *(const float4*)bp;
    float4 b1 = *(const float4*)(bp + 4);
    const float* bb = (const float*)&b0;
    const float* bb2 = (const float*)&b1;
    h16x8 ov;
#pragma unroll
    for (int j = 0; j < 8; ++j) {
      float o = acc[j] * inv + (j < 4 ? bb[j] : bb2[j - 4]);
      o = o > 0.f ? o : expm1f(o);
      ov[j] = (h16)o;
    }
    *(h16x8*)(outA + (unsigned)n * HC + s * 512 + lane * 8) = ov;
  } else {
    float t8[8];
#pragma unroll
    for (int j = 0; j < 8; ++j) {
      t8[j] = acc[j] * inv;
      t8[j] += __shfl_xor(t8[j], 32);  // sum head pair
    }
    if (lane < 32) {
      float* dst = Fb3 + ((unsigned)n * NS + s) * CD + lane * 8;
      float4 o0 = {t8[0], t8[1], t8[2], t8[3]};
      float4 o1 = {t8[4], t8[5], t8[6], t8[7]};
      *(float4*)dst = o0;
      *(float4*)(dst + 4) = o1;
    }
  }
}

// ---------- head-mean + bias + L2 normalize + mean pool ----------
template <int H>
__global__ __launch_bounds__(256) void normpool_kernel(const float* __restrict__ Fb3,
                                                       const float* __restrict__ bias,
                                                       const int* __restrict__ batch,
                                                       float* __restrict__ pooled, int* __restrict__ cnt) {
  constexpr int NS = H / 2;
  int n = blockIdx.x, t = threadIdx.x;
  float mv = 0.f;
#pragma unroll
  for (int s = 0; s < NS; ++s) mv += Fb3[((size_t)n * NS + s) * CD + t];
  mv = mv * (1.f / H) + bias[t];
  float ss = mv * mv;
  ss += __shfl_xor(ss, 1);  ss += __shfl_xor(ss, 2);  ss += __shfl_xor(ss, 4);
  ss += __shfl_xor(ss, 8);  ss += __shfl_xor(ss, 16); ss += __shfl_xor(ss, 32);
  __shared__ float ws4[4];
  if ((t & 63) == 0) ws4[t >> 6] = ss;
  __syncthreads();
  float tot = ws4[0] + ws4[1] + ws4[2] + ws4[3];
  float scale = 1.f / fmaxf(sqrtf(tot), 1e-12f);
  int g = batch[n];
  atomicAdd(&pooled[(size_t)g * CD + t], mv * scale);
  if (t == 0) atomicAdd(&cnt[g], 1);
}

// ---------- pooled epilogue ----------
__global__ __launch_bounds__(256) void pool_div_kernel(float* __restrict__ pooled, const int* __restrict__ cnt) {
  int g = blockIdx.x, t = threadIdx.x;
  pooled[(size_t)g * CD + t] /= fmaxf((float)cnt[g], 1.f);
}

__global__ __launch_bounds__(256) void mlp1_kernel(const float* __restrict__ pooled, const float* __restrict__ w,
                                                   const float* __restrict__ b, float* __restrict__ hid) {
  __shared__ float xs[CD];
  int g = blockIdx.x, t = threadIdx.x;
  xs[t] = pooled[(size_t)g * CD + t];
  __syncthreads();
  float acc = b[t];
  for (int k = 0; k < CD; ++k) acc += xs[k] * w[(size_t)t * CD + k];
  hid[(size_t)g * CD + t] = fmaxf(acc, 0.f);
}

__global__ __launch_bounds__(256) void mlp2_kernel(const float* __restrict__ hid, const float* __restrict__ w,
                                                   const float* __restrict__ b, float* __restrict__ out) {
  __shared__ float xs[CD];
  int g = blockIdx.x, t = threadIdx.x;
  xs[t] = hid[(size_t)g * CD + t];
  __syncthreads();
  for (int o = t; o < 768; o += 256) {
    float acc = b[o];
    for (int k = 0; k < CD; ++k) acc += xs[k] * w[(size_t)o * CD + k];
    out[(size_t)g * 768 + o] = acc;
  }
}

extern "C" void kernel_launch(void* const* d_in, const int* in_sizes, int n_in,
                              void* d_out, int out_size, void* d_ws, size_t ws_size,
                              hipStream_t stream) {
  const float* x      = (const float*)d_in[0];
  const int*   ei     = (const int*)d_in[1];
  const int*   batch  = (const int*)d_in[2];
  const float* c1_wl  = (const float*)d_in[3];
  const float* c1_wr  = (const float*)d_in[4];
  const float* c1_att = (const float*)d_in[5];
  const float* c1_b   = (const float*)d_in[6];
  const float* c2_wl  = (const float*)d_in[7];
  const float* c2_wr  = (const float*)d_in[8];
  const float* c2_att = (const float*)d_in[9];
  const float* c2_b   = (const float*)d_in[10];
  const float* c3_wl  = (const float*)d_in[11];
  const float* c3_wr  = (const float*)d_in[12];
  const float* c3_att = (const float*)d_in[13];
  const float* c3_b   = (const float*)d_in[14];
  const float* fp1_w  = (const float*)d_in[15];
  const float* fp1_b  = (const float*)d_in[16];
  const float* fp2_w  = (const float*)d_in[17];
  const float* fp2_b  = (const float*)d_in[18];

  char* p = (char*)d_ws;
  size_t off = 0;
  auto alloc = [&](size_t b) { void* r = p + off; off += (b + 255) & ~(size_t)255; return r; };
  h16*  A    = (h16*)alloc((size_t)NPAD * 1024 * 2);   // conv in/out feature buffer
  h16*  Xa   = (h16*)alloc((size_t)NPAD * 3072 * 2);   // X1 (2048 used) and X3 (3072)
  h16*  Xb   = (h16*)alloc((size_t)NPAD * 2048 * 2);   // X2; A1 aliases head; Fb3 aliases later
  h16*  A1   = Xb;                                     // fp16 input (dead before X2 written)
  float* Fb3 = (float*)Xb;                             // [NN][3][CD] fp32 (Xb dead after conv2 sagg)
  h16*  W1   = (h16*)alloc((size_t)2048 * K1P * 2);
  h16*  W2   = (h16*)alloc((size_t)2048 * 1024 * 2);
  h16*  W3   = (h16*)alloc((size_t)3072 * 1024 * 2);
  h16*  attH1 = (h16*)alloc((size_t)4 * CD * 2);
  h16*  attH2 = (h16*)alloc((size_t)4 * CD * 2);
  h16*  attH3 = (h16*)alloc((size_t)6 * CD * 2);
  int*  srcA   = (int*)alloc((size_t)NE * 4);
  int*  dstA   = (int*)alloc((size_t)NE * 4);
  int*  esrc   = (int*)alloc((size_t)NE * 4);
  int*  deg    = (int*)alloc((size_t)NN * 4);
  int*  cursor = (int*)alloc((size_t)NN * 4);
  int*  rowptr = (int*)alloc((size_t)(NN + 1) * 4);
  float* pooled = (float*)alloc((size_t)NG * CD * 4);
  int*  cnt    = (int*)alloc((size_t)NG * 4);
  float* hid   = (float*)alloc((size_t)NG * CD * 4);

  hipMemsetAsync(deg, 0, (size_t)NN * 4, stream);
  hipMemsetAsync(cursor, 0, (size_t)NN * 4, stream);
  hipMemsetAsync(pooled, 0, (size_t)NG * CD * 4, stream);
  hipMemsetAsync(cnt, 0, (size_t)NG * 4, stream);

  fill_x_kernel<<<NPAD, 256, 0, stream>>>(x, A1);
  conv_w2_kernel<<<2048, 256, 0, stream>>>(c1_wl, c1_wr, W1, 1024, FIN, K1P);
  conv_w2_kernel<<<2048, 256, 0, stream>>>(c2_wl, c2_wr, W2, 1024, 1024, 1024);
  conv_w2_kernel<<<3072, 256, 0, stream>>>(c3_wl, c3_wr, W3, 1536, 1024, 1024);
  attcvt_kernel<<<4, 256, 0, stream>>>(c1_att, attH1, 4 * CD);
  attcvt_kernel<<<4, 256, 0, stream>>>(c2_att, attH2, 4 * CD);
  attcvt_kernel<<<6, 256, 0, stream>>>(c3_att, attH3, 6 * CD);

  int eb = (NE + 255) / 256;
  build_edges_kernel<<<eb, 256, 0, stream>>>(ei, srcA, dstA);
  deg_kernel<<<eb, 256, 0, stream>>>(dstA, deg);
  scan_kernel<<<1, 1024, 0, stream>>>(deg, rowptr);
  scatter_kernel<<<eb, 256, 0, stream>>>(srcA, dstA, rowptr, cursor, esrc);

  // conv1: [NPAD,384] x [2048,384]^T -> Xa [NPAD,2048] = [XL|XR]
  gemm256_kernel<<<79 * 8, 512, 0, stream>>>(A1, W1, Xa, K1P, 2048, 8);
  sagg_kernel<4, 0><<<NN * 2 / 4, 256, 0, stream>>>(Xa, rowptr, esrc, attH1, c1_b, A, nullptr);

  // conv2: [NPAD,1024] x [2048,1024]^T -> Xb
  gemm256_kernel<<<79 * 8, 512, 0, stream>>>(A, W2, Xb, 1024, 2048, 8);
  sagg_kernel<4, 0><<<NN * 2 / 4, 256, 0, stream>>>(Xb, rowptr, esrc, attH2, c2_b, A, nullptr);

  // conv3: [NPAD,1024] x [3072,1024]^T -> Xa  (Xb dead from here; Fb3 aliases it)
  gemm256_kernel<<<79 * 12, 512, 0, stream>>>(A, W3, Xa, 1024, 3072, 12);
  sagg_kernel<6, 1><<<NN * 3 / 4, 256, 0, stream>>>(Xa, rowptr, esrc, attH3, nullptr, nullptr, Fb3);
  normpool_kernel<6><<<NN, 256, 0, stream>>>(Fb3, c3_b, batch, pooled, cnt);

  pool_div_kernel<<<NG, 256, 0, stream>>>(pooled, cnt);
  mlp1_kernel<<<NG, 256, 0, stream>>>(pooled, fp1_w, fp1_b, hid);
  mlp2_kernel<<<NG, 256, 0, stream>>>(hid, fp2_w, fp2_b, (float*)d_out);
}

// Round 9
// 695.023 us; speedup vs baseline: 1.2645x; 1.2645x over previous
//
#include <hip/hip_runtime.h>

typedef _Float16 h16;
typedef _Float16 h16x2 __attribute__((ext_vector_type(2)));
typedef _Float16 h16x4 __attribute__((ext_vector_type(4)));
typedef _Float16 h16x8 __attribute__((ext_vector_type(8)));
typedef float f32x4 __attribute__((ext_vector_type(4)));

static constexpr int NN   = 20000;   // nodes
static constexpr int NPAD = 20224;   // padded to 256-row tiles (79*256)
static constexpr int NE0  = 120000;  // raw edges
static constexpr int NE   = 140000;  // + self loops
static constexpr int NG   = 512;     // graphs
static constexpr int FIN  = 300;
static constexpr int K1P  = 384;     // FIN padded to K%64==0
static constexpr int CD   = 256;     // channels per head
static constexpr float SLOPE = 0.2f;

#define GLDS16(gsrc, ldst)                                                              \
  __builtin_amdgcn_global_load_lds(                                                    \
      (const __attribute__((address_space(1))) unsigned int*)(gsrc),                    \
      (__attribute__((address_space(3))) unsigned int*)(ldst), 16, 0, 0)

#define MFMA16(a, b, c) __builtin_amdgcn_mfma_f32_16x16x32_f16(a, b, c, 0, 0, 0)

// ---------- input conversion ----------
__global__ __launch_bounds__(256) void fill_x_kernel(const float* __restrict__ x, h16* __restrict__ a1) {
  int r = blockIdx.x;
  for (int c = threadIdx.x; c < K1P; c += 256) {
    float v = (r < NN && c < FIN) ? x[(size_t)r * FIN + c] : 0.f;
    a1[(size_t)r * K1P + c] = (h16)v;
  }
}

__global__ __launch_bounds__(256) void conv_w2_kernel(const float* __restrict__ wl, const float* __restrict__ wr,
                                                      h16* __restrict__ o, int rows, int cols, int colsp) {
  int r = blockIdx.x;  // 0 .. 2*rows-1
  const float* s = (r < rows) ? (wl + (size_t)r * cols) : (wr + (size_t)(r - rows) * cols);
  for (int c = threadIdx.x; c < colsp; c += 256) {
    float v = (c < cols) ? s[c] : 0.f;
    o[(size_t)r * colsp + c] = (h16)v;
  }
}

__global__ __launch_bounds__(256) void attcvt_kernel(const float* __restrict__ a, h16* __restrict__ o, int n) {
  int i = blockIdx.x * 256 + threadIdx.x;
  if (i < n) o[i] = (h16)a[i];
}

// ---------- CSR build ----------
__global__ __launch_bounds__(256) void build_edges_kernel(const int* __restrict__ ei,
                                                          int* __restrict__ src, int* __restrict__ dst) {
  int e = blockIdx.x * 256 + threadIdx.x;
  if (e >= NE) return;
  if (e < NE0) { src[e] = ei[e]; dst[e] = ei[NE0 + e]; }
  else         { src[e] = e - NE0; dst[e] = e - NE0; }
}

__global__ __launch_bounds__(256) void deg_kernel(const int* __restrict__ dst, int* __restrict__ deg) {
  int e = blockIdx.x * 256 + threadIdx.x;
  if (e < NE) atomicAdd(&deg[dst[e]], 1);
}

__global__ __launch_bounds__(1024) void scan_kernel(const int* __restrict__ deg, int* __restrict__ rowptr) {
  __shared__ int b0[1024], b1[1024];
  __shared__ int carry;
  int t = threadIdx.x;
  if (t == 0) carry = 0;
  __syncthreads();
  for (int base = 0; base < NN; base += 1024) {
    int x = (base + t < NN) ? deg[base + t] : 0;
    b0[t] = x;
    __syncthreads();
    int* cur = b0; int* nxt = b1;
    for (int off = 1; off < 1024; off <<= 1) {
      int v = cur[t];
      if (t >= off) v += cur[t - off];
      nxt[t] = v;
      __syncthreads();
      int* tmp = cur; cur = nxt; nxt = tmp;
    }
    if (base + t < NN) rowptr[base + t] = carry + cur[t] - x;  // exclusive
    __syncthreads();
    if (t == 0) carry += cur[1023];
    __syncthreads();
  }
  if (t == 0) rowptr[NN] = carry;
}

__global__ __launch_bounds__(256) void scatter_kernel(const int* __restrict__ src, const int* __restrict__ dst,
                                                      const int* __restrict__ rowptr, int* __restrict__ cursor,
                                                      int* __restrict__ esrc) {
  int e = blockIdx.x * 256 + threadIdx.x;
  if (e >= NE) return;
  int d = dst[e];
  int pos = rowptr[d] + atomicAdd(&cursor[d], 1);
  esrc[pos] = src[e];
}

// ---------- fp16 MFMA GEMM, 256x256 tile, BK=64, 8 waves ----------
// Counted-vmcnt double-buffer (sync skeleton verified r3-r8) + NEW: 4-phase
// {ds_read subtile -> setprio MFMA quad} interleave within the compute region.
// Waves desync between barriers -> one wave's MFMA hides another's LDS reads.
__global__ __launch_bounds__(512, 2) void gemm256_kernel(const h16* __restrict__ A, const h16* __restrict__ B,
                                                         h16* __restrict__ Co, int K, int Nw, int ntN) {
  __shared__ __align__(16) h16 lds[4 * 16384];  // [buf][mat] regions of 256x64
  int nwg = gridDim.x;
  int q = nwg >> 3, r = nwg & 7;
  int xc = blockIdx.x & 7, idx = blockIdx.x >> 3;
  int logical = (xc < r ? xc * (q + 1) : r * (q + 1) + (xc - r) * q) + idx;
  int tm = (logical / ntN) * 256, tn = (logical % ntN) * 256;

  int tid = threadIdx.x;
  int wv = tid >> 6, lane = tid & 63;
  int wm = (wv >> 2) * 128, wn = (wv & 3) * 64;
  int lrow = lane & 15, kq = lane >> 4, lr7 = lrow & 7;

  int rowoff = tid >> 3;
  int ug = ((tid & 7) ^ (rowoff & 7)) * 8;  // pre-swizzled global 16B-unit (in h16 elems)
  int ldsoff = (tid >> 6) * 512;

  const int NT = K >> 6;

  auto STAGE = [&](int buf, int kt) {
#pragma unroll
    for (int j = 0; j < 4; ++j) {
      GLDS16(A + (size_t)(tm + j * 64 + rowoff) * K + kt * 64 + ug,
             &lds[(buf * 2 + 0) * 16384 + j * 4096 + ldsoff]);
      GLDS16(B + (size_t)(tn + j * 64 + rowoff) * K + kt * 64 + ug,
             &lds[(buf * 2 + 1) * 16384 + j * 4096 + ldsoff]);
    }
  };

  STAGE(0, 0);
  STAGE(1, 1);

  f32x4 acc[8][4] = {};
  for (int t = 0; t < NT; ++t) {
    int b = t & 1;
    if (t + 1 < NT) { asm volatile("s_waitcnt vmcnt(8)" ::: "memory"); }
    else            { asm volatile("s_waitcnt vmcnt(0)" ::: "memory"); }
    __builtin_amdgcn_s_barrier();  // all waves' portions of buffer b have landed

    const h16* As_ = &lds[(b * 2 + 0) * 16384];
    const h16* Bs_ = &lds[(b * 2 + 1) * 16384];
    int u0 = (kq ^ lr7) * 8;        // k-slice 0 unit
    int u1 = ((4 + kq) ^ lr7) * 8;  // k-slice 1 unit
    h16x8 af[8], bf[4];

    // ---- phase 0: A(ks0) + B cols 0-1 (ks0) -> 16 MFMA (all rows x cols 0-1)
#pragma unroll
    for (int i = 0; i < 8; ++i) af[i] = *(const h16x8*)&As_[(wm + i * 16 + lrow) * 64 + u0];
    bf[0] = *(const h16x8*)&Bs_[(wn + 0 * 16 + lrow) * 64 + u0];
    bf[1] = *(const h16x8*)&Bs_[(wn + 1 * 16 + lrow) * 64 + u0];
    __builtin_amdgcn_s_setprio(1);
#pragma unroll
    for (int i = 0; i < 8; ++i) {
      acc[i][0] = MFMA16(af[i], bf[0], acc[i][0]);
      acc[i][1] = MFMA16(af[i], bf[1], acc[i][1]);
    }
    __builtin_amdgcn_s_setprio(0);
    __builtin_amdgcn_sched_barrier(0);

    // ---- phase 1: B cols 2-3 (ks0) -> 16 MFMA (rows x cols 2-3)
    bf[2] = *(const h16x8*)&Bs_[(wn + 2 * 16 + lrow) * 64 + u0];
    bf[3] = *(const h16x8*)&Bs_[(wn + 3 * 16 + lrow) * 64 + u0];
    __builtin_amdgcn_s_setprio(1);
#pragma unroll
    for (int i = 0; i < 8; ++i) {
      acc[i][2] = MFMA16(af[i], bf[2], acc[i][2]);
      acc[i][3] = MFMA16(af[i], bf[3], acc[i][3]);
    }
    __builtin_amdgcn_s_setprio(0);
    __builtin_amdgcn_sched_barrier(0);

    // ---- phase 2: A(ks1) + B cols 0-1 (ks1) -> 16 MFMA
#pragma unroll
    for (int i = 0; i < 8; ++i) af[i] = *(const h16x8*)&As_[(wm + i * 16 + lrow) * 64 + u1];
    bf[0] = *(const h16x8*)&Bs_[(wn + 0 * 16 + lrow) * 64 + u1];
    bf[1] = *(const h16x8*)&Bs_[(wn + 1 * 16 + lrow) * 64 + u1];
    __builtin_amdgcn_s_setprio(1);
#pragma unroll
    for (int i = 0; i < 8; ++i) {
      acc[i][0] = MFMA16(af[i], bf[0], acc[i][0]);
      acc[i][1] = MFMA16(af[i], bf[1], acc[i][1]);
    }
    __builtin_amdgcn_s_setprio(0);
    __builtin_amdgcn_sched_barrier(0);

    // ---- phase 3: B cols 2-3 (ks1); drain reads; barrier; restage; final 16 MFMA
    bf[2] = *(const h16x8*)&Bs_[(wn + 2 * 16 + lrow) * 64 + u1];
    bf[3] = *(const h16x8*)&Bs_[(wn + 3 * 16 + lrow) * 64 + u1];
    asm volatile("s_waitcnt lgkmcnt(0)" ::: "memory");
    __builtin_amdgcn_sched_barrier(0);
    __builtin_amdgcn_s_barrier();  // all waves done reading buffer b -> safe to restage
    if (t + 2 < NT) STAGE(b, t + 2);
    __builtin_amdgcn_s_setprio(1);
#pragma unroll
    for (int i = 0; i < 8; ++i) {
      acc[i][2] = MFMA16(af[i], bf[2], acc[i][2]);
      acc[i][3] = MFMA16(af[i], bf[3], acc[i][3]);
    }
    __builtin_amdgcn_s_setprio(0);
  }

  int cr = kq * 4, cc = lrow;
#pragma unroll
  for (int i = 0; i < 8; ++i)
#pragma unroll
    for (int j = 0; j < 4; ++j) {
      size_t base = (size_t)(tm + wm + i * 16 + cr) * Nw + (tn + wn + j * 16 + cc);
#pragma unroll
      for (int qq = 0; qq < 4; qq++) Co[base + (size_t)qq * Nw] = (h16)acc[i][j][qq];
    }
}

// ---------- fused score + online-softmax + aggregate (r4-best: wave per head) ----------
// X row layout: [ xl (H*CD) | xr (H*CD) ], stride S = 2*H*CD.
template <int H, int MODE>
__global__ __launch_bounds__(64 * H) void sagg_kernel(
    const h16* __restrict__ X, const int* __restrict__ rowptr, const int* __restrict__ esrc,
    const h16* __restrict__ attH, const float* __restrict__ bias,
    h16* __restrict__ outA, const int* __restrict__ batch,
    float* __restrict__ pooled, int* __restrict__ cnt) {
  constexpr int HC = H * CD, S = 2 * HC;
  int n = blockIdx.x;
  int tid = threadIdx.x, w = tid >> 6, lane = tid & 63;
  int cb = w * CD + lane * 4;

  h16x4 aw4 = *(const h16x4*)(attH + cb);
  h16x2 alo = __builtin_shufflevector(aw4, aw4, 0, 1);
  h16x2 ahi = __builtin_shufflevector(aw4, aw4, 2, 3);
  h16x4 xr4 = *(const h16x4*)(X + (size_t)n * S + HC + cb);

  int beg = rowptr[n], end = rowptr[n + 1];
  float m = -1e30f, s = 0.f;
  f32x4 a = {};
  int i = beg;
  while (i < end) {
    int cn = end - i; if (cn > 8) cn = 8;
    int js[8];
    h16x4 xs[8];
    float ps[8];
#pragma unroll
    for (int k = 0; k < 8; ++k) js[k] = esrc[i + (k < cn ? k : cn - 1)];  // independent loads
#pragma unroll
    for (int k = 0; k < 8; ++k) xs[k] = *(const h16x4*)(X + (size_t)js[k] * S + cb);  // batched gathers
#pragma unroll
    for (int k = 0; k < 8; ++k) {
      h16x4 v = xs[k] + xr4;                       // v_pk_add_f16
      h16x4 t = v * (h16)SLOPE;                    // v_pk_mul_f16
      v = __builtin_elementwise_max(v, t);         // leaky_relu = max(x, 0.2x)
      float p = __builtin_amdgcn_fdot2(__builtin_shufflevector(v, v, 0, 1), alo,
                __builtin_amdgcn_fdot2(__builtin_shufflevector(v, v, 2, 3), ahi, 0.f, false), false);
      p += __shfl_xor(p, 32); p += __shfl_xor(p, 16); p += __shfl_xor(p, 8);
      p += __shfl_xor(p, 4);  p += __shfl_xor(p, 2);  p += __shfl_xor(p, 1);
      ps[k] = p;
    }
#pragma unroll
    for (int k = 0; k < 8; ++k) {
      if (k < cn) {
        float p = ps[k];
        if (p <= m) {            // wave-uniform branch: no rescale (common case)
          float we = __expf(p - m);
          s += we;
          a[0] += we * (float)xs[k][0]; a[1] += we * (float)xs[k][1];
          a[2] += we * (float)xs[k][2]; a[3] += we * (float)xs[k][3];
        } else {                 // new max: rescale, we = 1
          float f = __expf(m - p);
          s = s * f + 1.f;
          a[0] = a[0] * f + (float)xs[k][0]; a[1] = a[1] * f + (float)xs[k][1];
          a[2] = a[2] * f + (float)xs[k][2]; a[3] = a[3] * f + (float)xs[k][3];
          m = p;
        }
      }
    }
    i += cn;
  }
  float inv = 1.f / (s + 1e-16f);

  if (MODE == 0) {
    float o0 = a[0] * inv + bias[cb + 0];
    float o1 = a[1] * inv + bias[cb + 1];
    float o2 = a[2] * inv + bias[cb + 2];
    float o3 = a[3] * inv + bias[cb + 3];
    o0 = o0 > 0.f ? o0 : expm1f(o0);
    o1 = o1 > 0.f ? o1 : expm1f(o1);
    o2 = o2 > 0.f ? o2 : expm1f(o2);
    o3 = o3 > 0.f ? o3 : expm1f(o3);
    h16x4 ov = {(h16)o0, (h16)o1, (h16)o2, (h16)o3};
    *(h16x4*)(outA + (size_t)n * HC + cb) = ov;
  } else {
    __shared__ float sh[HC];
    __shared__ float red[H];
    float4 nv = {a[0] * inv, a[1] * inv, a[2] * inv, a[3] * inv};
    *(float4*)&sh[cb] = nv;
    __syncthreads();
    float mv = 0.f;
    if (tid < CD) {
#pragma unroll
      for (int h = 0; h < H; h++) mv += sh[h * CD + tid];
      mv = mv * (1.f / H) + bias[tid];
    }
    float ss = (tid < CD) ? mv * mv : 0.f;
    ss += __shfl_xor(ss, 32); ss += __shfl_xor(ss, 16); ss += __shfl_xor(ss, 8);
    ss += __shfl_xor(ss, 4);  ss += __shfl_xor(ss, 2);  ss += __shfl_xor(ss, 1);
    if (lane == 0) red[w] = ss;
    __syncthreads();
    float tot = 0.f;
#pragma unroll
    for (int h = 0; h < H; h++) tot += red[h];
    float scale = 1.f / fmaxf(sqrtf(tot), 1e-12f);
    int g = batch[n];
    if (tid < CD) atomicAdd(&pooled[(size_t)g * CD + tid], mv * scale);
    if (tid == 0) atomicAdd(&cnt[g], 1);
  }
}

// ---------- pooled epilogue ----------
__global__ __launch_bounds__(256) void pool_div_kernel(float* __restrict__ pooled, const int* __restrict__ cnt) {
  int g = blockIdx.x, t = threadIdx.x;
  pooled[(size_t)g * CD + t] /= fmaxf((float)cnt[g], 1.f);
}

__global__ __launch_bounds__(256) void mlp1_kernel(const float* __restrict__ pooled, const float* __restrict__ w,
                                                   const float* __restrict__ b, float* __restrict__ hid) {
  __shared__ float xs[CD];
  int g = blockIdx.x, t = threadIdx.x;
  xs[t] = pooled[(size_t)g * CD + t];
  __syncthreads();
  float acc = b[t];
  for (int k = 0; k < CD; ++k) acc += xs[k] * w[(size_t)t * CD + k];
  hid[(size_t)g * CD + t] = fmaxf(acc, 0.f);
}

__global__ __launch_bounds__(256) void mlp2_kernel(const float* __restrict__ hid, const float* __restrict__ w,
                                                   const float* __restrict__ b, float* __restrict__ out) {
  __shared__ float xs[CD];
  int g = blockIdx.x, t = threadIdx.x;
  xs[t] = hid[(size_t)g * CD + t];
  __syncthreads();
  for (int o = t; o < 768; o += 256) {
    float acc = b[o];
    for (int k = 0; k < CD; ++k) acc += xs[k] * w[(size_t)o * CD + k];
    out[(size_t)g * 768 + o] = acc;
  }
}

extern "C" void kernel_launch(void* const* d_in, const int* in_sizes, int n_in,
                              void* d_out, int out_size, void* d_ws, size_t ws_size,
                              hipStream_t stream) {
  const float* x      = (const float*)d_in[0];
  const int*   ei     = (const int*)d_in[1];
  const int*   batch  = (const int*)d_in[2];
  const float* c1_wl  = (const float*)d_in[3];
  const float* c1_wr  = (const float*)d_in[4];
  const float* c1_att = (const float*)d_in[5];
  const float* c1_b   = (const float*)d_in[6];
  const float* c2_wl  = (const float*)d_in[7];
  const float* c2_wr  = (const float*)d_in[8];
  const float* c2_att = (const float*)d_in[9];
  const float* c2_b   = (const float*)d_in[10];
  const float* c3_wl  = (const float*)d_in[11];
  const float* c3_wr  = (const float*)d_in[12];
  const float* c3_att = (const float*)d_in[13];
  const float* c3_b   = (const float*)d_in[14];
  const float* fp1_w  = (const float*)d_in[15];
  const float* fp1_b  = (const float*)d_in[16];
  const float* fp2_w  = (const float*)d_in[17];
  const float* fp2_b  = (const float*)d_in[18];

  char* p = (char*)d_ws;
  size_t off = 0;
  auto alloc = [&](size_t b) { void* r = p + off; off += (b + 255) & ~(size_t)255; return r; };
  h16*  A    = (h16*)alloc((size_t)NPAD * 1024 * 2);   // conv in/out feature buffer
  h16*  Xa   = (h16*)alloc((size_t)NPAD * 3072 * 2);   // X1 (2048 used) and X3 (3072)
  h16*  Xb   = (h16*)alloc((size_t)NPAD * 2048 * 2);   // X2; A1 aliases its head
  h16*  A1   = Xb;                                     // [NPAD][384] fp16 input (dead before X2 written)
  h16*  W1   = (h16*)alloc((size_t)2048 * K1P * 2);
  h16*  W2   = (h16*)alloc((size_t)2048 * 1024 * 2);
  h16*  W3   = (h16*)alloc((size_t)3072 * 1024 * 2);
  h16*  attH1 = (h16*)alloc((size_t)4 * CD * 2);
  h16*  attH2 = (h16*)alloc((size_t)4 * CD * 2);
  h16*  attH3 = (h16*)alloc((size_t)6 * CD * 2);
  int*  srcA   = (int*)alloc((size_t)NE * 4);
  int*  dstA   = (int*)alloc((size_t)NE * 4);
  int*  esrc   = (int*)alloc((size_t)NE * 4);
  int*  deg    = (int*)alloc((size_t)NN * 4);
  int*  cursor = (int*)alloc((size_t)NN * 4);
  int*  rowptr = (int*)alloc((size_t)(NN + 1) * 4);
  float* pooled = (float*)alloc((size_t)NG * CD * 4);
  int*  cnt    = (int*)alloc((size_t)NG * 4);
  float* hid   = (float*)alloc((size_t)NG * CD * 4);

  hipMemsetAsync(deg, 0, (size_t)NN * 4, stream);
  hipMemsetAsync(cursor, 0, (size_t)NN * 4, stream);
  hipMemsetAsync(pooled, 0, (size_t)NG * CD * 4, stream);
  hipMemsetAsync(cnt, 0, (size_t)NG * 4, stream);

  fill_x_kernel<<<NPAD, 256, 0, stream>>>(x, A1);
  conv_w2_kernel<<<2048, 256, 0, stream>>>(c1_wl, c1_wr, W1, 1024, FIN, K1P);
  conv_w2_kernel<<<2048, 256, 0, stream>>>(c2_wl, c2_wr, W2, 1024, 1024, 1024);
  conv_w2_kernel<<<3072, 256, 0, stream>>>(c3_wl, c3_wr, W3, 1536, 1024, 1024);
  attcvt_kernel<<<4, 256, 0, stream>>>(c1_att, attH1, 4 * CD);
  attcvt_kernel<<<4, 256, 0, stream>>>(c2_att, attH2, 4 * CD);
  attcvt_kernel<<<6, 256, 0, stream>>>(c3_att, attH3, 6 * CD);

  int eb = (NE + 255) / 256;
  build_edges_kernel<<<eb, 256, 0, stream>>>(ei, srcA, dstA);
  deg_kernel<<<eb, 256, 0, stream>>>(dstA, deg);
  scan_kernel<<<1, 1024, 0, stream>>>(deg, rowptr);
  scatter_kernel<<<eb, 256, 0, stream>>>(srcA, dstA, rowptr, cursor, esrc);

  // conv1: [NPAD,384] x [2048,384]^T -> Xa [NPAD,2048] = [XL|XR]
  gemm256_kernel<<<79 * 8, 512, 0, stream>>>(A1, W1, Xa, K1P, 2048, 8);
  sagg_kernel<4, 0><<<NN, 256, 0, stream>>>(Xa, rowptr, esrc, attH1, c1_b, A, nullptr, nullptr, nullptr);

  // conv2: [NPAD,1024] x [2048,1024]^T -> Xb
  gemm256_kernel<<<79 * 8, 512, 0, stream>>>(A, W2, Xb, 1024, 2048, 8);
  sagg_kernel<4, 0><<<NN, 256, 0, stream>>>(Xb, rowptr, esrc, attH2, c2_b, A, nullptr, nullptr, nullptr);

  // conv3: [NPAD,1024] x [3072,1024]^T -> Xa [NPAD,3072]
  gemm256_kernel<<<79 * 12, 512, 0, stream>>>(A, W3, Xa, 1024, 3072, 12);
  sagg_kernel<6, 1><<<NN, 384, 0, stream>>>(Xa, rowptr, esrc, attH3, c3_b, nullptr, batch, pooled, cnt);

  pool_div_kernel<<<NG, 256, 0, stream>>>(pooled, cnt);
  mlp1_kernel<<<NG, 256, 0, stream>>>(pooled, fp1_w, fp1_b, hid);
  mlp2_kernel<<<NG, 256, 0, stream>>>(hid, fp2_w, fp2_b, (float*)d_out);
}